// Round 12
// baseline (299.123 us; speedup 1.0000x reference)
//
#include <hip/hip_runtime.h>
#include <hip/hip_bf16.h>

#define N_NODES 50000
#define N_EDGES 800000
#define C 128

#define NBB   391      // buckets of 128 nodes: bucket = dst >> 7
#define CAPB  3072     // tmp per-bucket capacity (mean 2046, +22 sigma)
#define CAPC  3456     // csr per-bucket capacity (CAPB + 128*3 pad)
#define CHUNK 2048     // edges per binA block

#define NSL     4          // channel slices (32 ch = 64 B rows; 3.2 MB/slice table)
#define SL_U4   200000     // uint4 per slice (50000 rows x 4)
#define SL_US   1600000    // ushort per slice
#define BPS     12500      // agg blocks per slice (4 nodes/block, 1 wave/node)

typedef __attribute__((ext_vector_type(8))) short short8v;  // 8 bf16 (4 VGPR)
typedef __attribute__((ext_vector_type(4))) float f32x4;    // MFMA C/D

// ---------------------------------------------------------------------------
// bf16 pack helpers (RTN)
// ---------------------------------------------------------------------------
__device__ __forceinline__ unsigned int bf16rtn(float f) {
    unsigned int u = __float_as_uint(f);
    return (u + 0x7fffu + ((u >> 16) & 1u)) >> 16;
}
__device__ __forceinline__ unsigned int packbf2(float lo, float hi) {
    return bf16rtn(lo) | (bf16rtn(hi) << 16);
}

// ---------------------------------------------------------------------------
// k_prepW: split W (f32 [k][col]) into Wh + Wl bf16 stored [col][k] (B^T rows
// = MFMA B-frag layout). Also zeroes gcur.
// ---------------------------------------------------------------------------
__global__ void k_prepW(const float* __restrict__ W1, const float* __restrict__ W2,
                        unsigned short* __restrict__ Wsplit, int* __restrict__ gcur) {
    int t = blockIdx.x * 256 + threadIdx.x;   // 0..32767
    if (t < NBB) gcur[t] = 0;
    if (t >= 32768) return;
    int layer = t >> 14, idx = t & 16383;
    int i = idx >> 7, j = idx & 127;          // i = k (in), j = col (out)
    const float* Wsrc = layer ? W2 : W1;
    float w = Wsrc[i * 128 + j];
    unsigned int h = bf16rtn(w);
    float hf = __uint_as_float(h << 16);
    unsigned int l = bf16rtn(w - hf);
    unsigned short* base = Wsplit + layer * 32768;
    base[j * 128 + i] = (unsigned short)h;
    base[16384 + j * 128 + i] = (unsigned short)l;
}

// ---------------------------------------------------------------------------
// k_binA: single-level radix partition (shfl scan) — unchanged.
// ---------------------------------------------------------------------------
__global__ __launch_bounds__(256) void k_binA(const int* __restrict__ ei,
                                              int* __restrict__ gcur,
                                              int2* __restrict__ tmp) {
    __shared__ int hist[NBB];
    __shared__ int lbase[NBB];
    __shared__ int gbaseL[NBB];
    __shared__ int wsum[4];
    __shared__ int2 buf[CHUNK];
    __shared__ int totalv;

    int tid = threadIdx.x;
    int e0 = blockIdx.x * CHUNK;

    for (int i = tid; i < NBB; i += 256) hist[i] = 0;
    __syncthreads();

    int sarr[8], darr[8], parr[8];
#pragma unroll
    for (int j = 0; j < 8; ++j) {
        int e = e0 + j * 256 + tid;
        darr[j] = -1;
        if (e < N_EDGES) {
            sarr[j] = ei[e];
            int d = ei[N_EDGES + e];
            darr[j] = d;
            parr[j] = atomicAdd(&hist[d >> 7], 1);
        }
    }
    __syncthreads();

    {   // exclusive scan of hist (thread t owns buckets 2t,2t+1); shfl scan
        int i0 = 2 * tid, i1 = i0 + 1;
        int c0 = (i0 < NBB) ? hist[i0] : 0;
        int c1 = (i1 < NBB) ? hist[i1] : 0;
        int c = c0 + c1;
        int lane = tid & 63, w = tid >> 6;
        int s = c;
#pragma unroll
        for (int d = 1; d < 64; d <<= 1) {
            int u = __shfl_up(s, d, 64);
            if (lane >= d) s += u;
        }
        if (lane == 63) wsum[w] = s;
        __syncthreads();
        int add = 0;
        for (int i = 0; i < w; ++i) add += wsum[i];
        int incl = s + add;
        int excl = incl - c;
        if (i0 < NBB) lbase[i0] = excl;
        if (i1 < NBB) lbase[i1] = excl + c0;
        if (tid == 255) totalv = incl;
    }
    for (int i = tid; i < NBB; i += 256) {
        int cnt = hist[i];
        int run = (cnt > 0) ? atomicAdd(&gcur[i], cnt) : 0;
        gbaseL[i] = i * CAPB + run;
    }
    __syncthreads();

#pragma unroll
    for (int j = 0; j < 8; ++j) {
        if (darr[j] >= 0) {
            int b = darr[j] >> 7;
            buf[lbase[b] + parr[j]] = make_int2(sarr[j], darr[j]);
        }
    }
    __syncthreads();

    int total = totalv;
    for (int i = tid; i < total; i += 256) {
        int2 v = buf[i];
        int b = v.y >> 7;
        int gpos = gbaseL[b] + (i - lbase[b]);
        if (gpos < (b + 1) * CAPB) tmp[gpos] = v;
    }
}

// ---------------------------------------------------------------------------
// k_csr: one block per bucket; per-node contiguous lists + offn/degn/dinv.
// ---------------------------------------------------------------------------
__global__ __launch_bounds__(256) void k_csr(const int2* __restrict__ tmp,
                                             const int* __restrict__ gcur,
                                             int* __restrict__ csr,
                                             int* __restrict__ offn,
                                             int* __restrict__ degn,
                                             float* __restrict__ dinv) {
    __shared__ int   rawsrc[CAPB];
    __shared__ short rawloc[CAPB];
    __shared__ int   lcnt[128];
    __shared__ int   lbase[128];
    __shared__ int   lcur[128];

    int b = blockIdx.x, tid = threadIdx.x;
    int cnt = gcur[b];
    if (cnt > CAPB) cnt = CAPB;

    if (tid < 128) { lcnt[tid] = 0; lcur[tid] = 0; }
    __syncthreads();

    const int2* tmpb = tmp + (size_t)b * CAPB;
    for (int i = tid; i < cnt; i += 256) {
        int2 v = tmpb[i];
        int l = v.y & 127;
        rawsrc[i] = v.x;
        rawloc[i] = (short)l;
        atomicAdd(&lcnt[l], 1);
    }
    __syncthreads();

    if (tid < 64) {   // scan of 4-padded counts (keeps each list 16B-aligned)
        int c0 = lcnt[2 * tid], c1 = lcnt[2 * tid + 1];
        int p0 = (c0 + 3) & ~3, p1 = (c1 + 3) & ~3;
        int c = p0 + p1;
        int s = c;
#pragma unroll
        for (int d = 1; d < 64; d <<= 1) {
            int u = __shfl_up(s, d, 64);
            if (tid >= d) s += u;
        }
        int excl = s - c;
        lbase[2 * tid] = excl;
        lbase[2 * tid + 1] = excl + p0;
    }
    __syncthreads();

    int node = b * 128 + tid;
    if (tid < 128 && node < N_NODES) {
        offn[node] = b * CAPC + lbase[tid];
        degn[node] = lcnt[tid];
        dinv[node] = rsqrtf((float)lcnt[tid] + 1.0f);
    }

    for (int i = tid; i < cnt; i += 256) {
        int l = rawloc[i];
        int p = atomicAdd(&lcur[l], 1);
        csr[b * CAPC + lbase[l] + p] = rawsrc[i];
    }
}

// ---------------------------------------------------------------------------
// MFMA GEMM (2-term W-split) -> SLICE-MAJOR pre-scaled bf16 h. Unchanged.
// ---------------------------------------------------------------------------
template <bool AF32>
__global__ __launch_bounds__(512, 4) void k_gemm(const void* __restrict__ Ain,
                                                 const unsigned short* __restrict__ Whg,
                                                 const unsigned short* __restrict__ Wlg,
                                                 const float* __restrict__ dinv,
                                                 unsigned short* __restrict__ Hout) {
    __shared__ uint4 Al[64 * 16];   // [64 rows][128 k] bf16, XOR-swizzled
    __shared__ float ddv[64];

    int tid = threadIdx.x;
    int row0 = blockIdx.x * 64;
    int wv = tid >> 6, lane = tid & 63;
    int col = wv * 16 + (lane & 15);
    int kq = lane >> 4;

    const uint4* Bh4 = (const uint4*)Whg;
    const uint4* Bl4 = (const uint4*)Wlg;
    short8v bh[4], bl[4];
#pragma unroll
    for (int ks = 0; ks < 4; ++ks) {
        uint4 uh = Bh4[col * 16 + ks * 4 + kq];
        uint4 ul = Bl4[col * 16 + ks * 4 + kq];
        bh[ks] = *reinterpret_cast<short8v*>(&uh);
        bl[ks] = *reinterpret_cast<short8v*>(&ul);
    }

#pragma unroll
    for (int pass = 0; pass < 2; ++pass) {
        int row = (tid >> 4) + pass * 32;
        int o = tid & 15;
        int gr = row0 + row;
        uint4 u = make_uint4(0u, 0u, 0u, 0u);
        if (AF32) {
            float4 v0 = make_float4(0.f, 0.f, 0.f, 0.f), v1 = v0;
            if (gr < N_NODES) {
                const float4* A4 = (const float4*)Ain;
                v0 = A4[gr * 32 + o * 2];
                v1 = A4[gr * 32 + o * 2 + 1];
            }
            u.x = packbf2(v0.x, v0.y);
            u.y = packbf2(v0.z, v0.w);
            u.z = packbf2(v1.x, v1.y);
            u.w = packbf2(v1.z, v1.w);
        } else {
            if (gr < N_NODES)   // slice-major read: slice o>>2, quad o&3
                u = ((const uint4*)Ain)[(size_t)(o >> 2) * SL_U4 + gr * 4 + (o & 3)];
        }
        int byte = (row * 256 + o * 16) ^ ((row & 7) << 4);
        Al[byte >> 4] = u;
    }
    if (tid < 64) {
        int gr = row0 + tid;
        ddv[tid] = (gr < N_NODES) ? dinv[gr] : 0.f;
    }
    __syncthreads();

    f32x4 acc[4];
#pragma unroll
    for (int st = 0; st < 4; ++st) acc[st] = (f32x4){0.f, 0.f, 0.f, 0.f};

#pragma unroll
    for (int st = 0; st < 4; ++st) {
        int rowl = st * 16 + (lane & 15);
        int rbase = rowl * 256;
        int swz = (rowl & 7) << 4;
#pragma unroll
        for (int ks = 0; ks < 4; ++ks) {
            int byte = (rbase + ks * 64 + kq * 16) ^ swz;
            uint4 ua = Al[byte >> 4];
            short8v a = *reinterpret_cast<short8v*>(&ua);
            acc[st] = __builtin_amdgcn_mfma_f32_16x16x32_bf16(a, bh[ks], acc[st], 0, 0, 0);
            acc[st] = __builtin_amdgcn_mfma_f32_16x16x32_bf16(a, bl[ks], acc[st], 0, 0, 0);
        }
    }

    // Epilogue: slice-major store. col fixed per lane; slice = col>>5.
    {
        int sl = col >> 5, cs = col & 31;
        unsigned short* Hs = Hout + (size_t)sl * SL_US + cs;
#pragma unroll
        for (int st = 0; st < 4; ++st) {
#pragma unroll
            for (int r = 0; r < 4; ++r) {
                int rowl = st * 16 + kq * 4 + r;
                int gr = row0 + rowl;
                if (gr < N_NODES)
                    Hs[gr * 32] = (unsigned short)bf16rtn(ddv[rowl] * acc[st][r]);
            }
        }
    }
}

// ---------------------------------------------------------------------------
// Slice-phased aggregation, wave-per-node (MLP restored). Grid = NSL*BPS
// blocks x 256 thr; 4 waves/block, 1 node-slice per wave. Lane = eg(0..15) |
// cq(0..3): per iteration one int2 index load + 2 x 64B row gathers per lane
// -> 32 edges (rows) in flight per wave. Slice tables (3.2MB) stay per-XCD
// L2-resident (round-11 FETCH evidence); csr NT-loaded to avoid thrash.
// FINAL=false: relu'd bf16 slice rows. FINAL=true: per-slice partial dot.
// ---------------------------------------------------------------------------
__device__ __forceinline__ void add8(float* acc, uint4 u) {
    acc[0] += __uint_as_float(u.x << 16);
    acc[1] += __uint_as_float(u.x & 0xffff0000u);
    acc[2] += __uint_as_float(u.y << 16);
    acc[3] += __uint_as_float(u.y & 0xffff0000u);
    acc[4] += __uint_as_float(u.z << 16);
    acc[5] += __uint_as_float(u.z & 0xffff0000u);
    acc[6] += __uint_as_float(u.w << 16);
    acc[7] += __uint_as_float(u.w & 0xffff0000u);
}

template <bool FINAL>
__global__ __launch_bounds__(256) void k_agg(const uint4* __restrict__ hall,
                                             const int* __restrict__ csr,
                                             const int* __restrict__ offn,
                                             const int* __restrict__ degn,
                                             const float* __restrict__ bias,
                                             const float* __restrict__ Wlin,
                                             void* __restrict__ outbuf) {
    int bid = blockIdx.x;
    int slice = bid / BPS;
    int nb = bid - slice * BPS;
    int wv = threadIdx.x >> 6, lane = threadIdx.x & 63;
    int eg = lane >> 2;           // edge group 0..15
    int cq = lane & 3;            // 16B quad within 64B row
    int n = nb * 4 + wv;          // < 50000 exactly

    const uint4* hs = hall + (size_t)slice * SL_U4;

    int o0 = offn[n];
    int deg = degn[n];
    int end = o0 + deg;

    uint4 us = hs[n * 4 + cq];    // self-term row (issue early)

    float acc[8];
#pragma unroll
    for (int k = 0; k < 8; ++k) acc[k] = 0.f;

    int e = o0;
    // 32 edges/iter: int2 indices, 2 x 64B rows in flight per lane
    for (; e + 32 <= end; e += 32) {
        int2 s2 = *(const int2*)(csr + e + 2 * eg);   // 8B-aligned (o0 16B-aligned)
        uint4 u0 = hs[s2.x * 4 + cq];
        uint4 u1 = hs[s2.y * 4 + cq];
        add8(acc, u0);
        add8(acc, u1);
    }
    if (e + 16 <= end) {
        int s = __builtin_nontemporal_load(csr + e + eg);
        uint4 u = hs[s * 4 + cq];
        add8(acc, u);
        e += 16;
    }
    {   // tail < 16
        int rem = end - e;
        if (eg < rem) {
            int s = __builtin_nontemporal_load(csr + e + eg);
            add8(acc, hs[s * 4 + cq]);
        }
    }
    // reduce across the 16 edge groups (lane bits 2..5)
#pragma unroll
    for (int k = 0; k < 8; ++k) {
        acc[k] += __shfl_xor(acc[k], 4, 64);
        acc[k] += __shfl_xor(acc[k], 8, 64);
        acc[k] += __shfl_xor(acc[k], 16, 64);
        acc[k] += __shfl_xor(acc[k], 32, 64);
    }

    float dv = rsqrtf((float)deg + 1.0f);
    float hv[8];
    hv[0] = __uint_as_float(us.x << 16); hv[1] = __uint_as_float(us.x & 0xffff0000u);
    hv[2] = __uint_as_float(us.y << 16); hv[3] = __uint_as_float(us.y & 0xffff0000u);
    hv[4] = __uint_as_float(us.z << 16); hv[5] = __uint_as_float(us.z & 0xffff0000u);
    hv[6] = __uint_as_float(us.w << 16); hv[7] = __uint_as_float(us.w & 0xffff0000u);
    float4 bv0 = ((const float4*)bias)[slice * 8 + cq * 2];
    float4 bv1 = ((const float4*)bias)[slice * 8 + cq * 2 + 1];
    float o[8];
    o[0] = dv * (acc[0] + hv[0]) + bv0.x;
    o[1] = dv * (acc[1] + hv[1]) + bv0.y;
    o[2] = dv * (acc[2] + hv[2]) + bv0.z;
    o[3] = dv * (acc[3] + hv[3]) + bv0.w;
    o[4] = dv * (acc[4] + hv[4]) + bv1.x;
    o[5] = dv * (acc[5] + hv[5]) + bv1.y;
    o[6] = dv * (acc[6] + hv[6]) + bv1.z;
    o[7] = dv * (acc[7] + hv[7]) + bv1.w;

    if (!FINAL) {
        if (eg == 0) {   // 4 writer lanes per node, one 64B coalesced row
            uint4 u;
            u.x = packbf2(fmaxf(o[0], 0.f), fmaxf(o[1], 0.f));
            u.y = packbf2(fmaxf(o[2], 0.f), fmaxf(o[3], 0.f));
            u.z = packbf2(fmaxf(o[4], 0.f), fmaxf(o[5], 0.f));
            u.w = packbf2(fmaxf(o[6], 0.f), fmaxf(o[7], 0.f));
            ((uint4*)outbuf)[(size_t)slice * SL_U4 + n * 4 + cq] = u;
        }
    } else {
        float4 wl0 = ((const float4*)Wlin)[slice * 8 + cq * 2];
        float4 wl1 = ((const float4*)Wlin)[slice * 8 + cq * 2 + 1];
        float v = fmaxf(o[0], 0.f) * wl0.x + fmaxf(o[1], 0.f) * wl0.y
                + fmaxf(o[2], 0.f) * wl0.z + fmaxf(o[3], 0.f) * wl0.w
                + fmaxf(o[4], 0.f) * wl1.x + fmaxf(o[5], 0.f) * wl1.y
                + fmaxf(o[6], 0.f) * wl1.z + fmaxf(o[7], 0.f) * wl1.w;
        v += __shfl_xor(v, 1, 64);   // reduce over cq
        v += __shfl_xor(v, 2, 64);
        if ((lane & 3) == 0 && eg == 0)
            __builtin_nontemporal_store(v, (float*)outbuf + slice * N_NODES + n);
    }
}

// ---------------------------------------------------------------------------
// k_fin: out[n] = sum_slices partial[s][n] + blin
// ---------------------------------------------------------------------------
__global__ void k_fin(const float* __restrict__ partial, const float* __restrict__ blin,
                      float* __restrict__ out) {
    int n = blockIdx.x * 256 + threadIdx.x;
    if (n < N_NODES)
        out[n] = ((partial[n] + partial[N_NODES + n])
                + (partial[2 * N_NODES + n] + partial[3 * N_NODES + n])) + blin[0];
}

// ---------------------------------------------------------------------------
extern "C" void kernel_launch(void* const* d_in, const int* in_sizes, int n_in,
                              void* d_out, int out_size, void* d_ws, size_t ws_size,
                              hipStream_t stream) {
    const float* x    = (const float*)d_in[0];
    const int*   ei   = (const int*)d_in[2];
    const float* W1   = (const float*)d_in[4];
    const float* b1   = (const float*)d_in[5];
    const float* W2   = (const float*)d_in[6];
    const float* b2   = (const float*)d_in[7];
    const float* Wlin = (const float*)d_in[8];
    const float* blin = (const float*)d_in[9];
    float* out = (float*)d_out;

    char* ws = (char*)d_ws;
    size_t off = 0;
    auto carve = [&](size_t bytes) -> void* {
        void* p = ws + off;
        off = (off + bytes + 255) & ~(size_t)255;
        return p;
    };
    int*   gcur = (int*)  carve(NBB * sizeof(int));
    float* dinv = (float*)carve(N_NODES * sizeof(float));
    int*   offn = (int*)  carve(N_NODES * sizeof(int));
    int*   degn = (int*)  carve(N_NODES * sizeof(int));
    int2*  tmp  = (int2*) carve((size_t)NBB * CAPB * sizeof(int2));   // 9.6 MB
    int*   csr  = (int*)  carve((size_t)NBB * CAPC * sizeof(int));    // 5.4 MB
    unsigned short* hbf  = (unsigned short*)carve((size_t)NSL * SL_US * sizeof(unsigned short));
    unsigned short* hbf2 = (unsigned short*)carve((size_t)NSL * SL_US * sizeof(unsigned short));
    float* partial = (float*)carve((size_t)NSL * N_NODES * sizeof(float));
    unsigned short* wsplit = (unsigned short*)carve(4 * 16384 * sizeof(unsigned short));

    const int NB_A = (N_EDGES + CHUNK - 1) / CHUNK;   // 391
    const int NB_G = (N_NODES + 63) / 64;             // 782
    const int NB_S = NSL * BPS;                       // 50000 agg blocks
    const int NB_F = (N_NODES + 255) / 256;           // 196

    const unsigned short* W1h = wsplit;
    const unsigned short* W1l = wsplit + 16384;
    const unsigned short* W2h = wsplit + 32768;
    const unsigned short* W2l = wsplit + 49152;

    // prep (zeroes gcur) -> partition -> CSR (+dinv)
    k_prepW<<<128, 256, 0, stream>>>(W1, W2, wsplit, gcur);
    k_binA<<<NB_A, 256, 0, stream>>>(ei, gcur, tmp);
    k_csr<<<NBB, 256, 0, stream>>>(tmp, gcur, csr, offn, degn, dinv);

    // Layer 1: h1 (slice-major) = bf16(dinv * (x @ W1)); agg1 -> relu'd slices
    k_gemm<true><<<NB_G, 512, 0, stream>>>(x, W1h, W1l, dinv, hbf);
    k_agg<false><<<NB_S, 256, 0, stream>>>((const uint4*)hbf, csr, offn, degn,
                                           b1, Wlin, hbf2);
    // Layer 2: h2 = bf16(dinv * (relu(agg1) @ W2)); agg2 -> per-slice partial dots
    k_gemm<false><<<NB_G, 512, 0, stream>>>(hbf2, W2h, W2l, dinv, hbf);
    k_agg<true><<<NB_S, 256, 0, stream>>>((const uint4*)hbf, csr, offn, degn,
                                          b2, Wlin, partial);
    // Final: sum slice partials + bias
    k_fin<<<NB_F, 256, 0, stream>>>(partial, blin, out);
}

// Round 13
// 200.264 us; speedup vs baseline: 1.4936x; 1.4936x over previous
//
#include <hip/hip_runtime.h>
#include <hip/hip_bf16.h>

#define N_NODES 50000
#define N_EDGES 800000
#define C 128

#define NBB   391      // buckets of 128 nodes: bucket = dst >> 7
#define CAPB  3072     // tmp per-bucket capacity (mean 2046, +22 sigma)
#define CAPC  3584     // csr per-bucket capacity in ushorts (CAPB + 128*3 pad + slack)
#define CHUNK 2048     // edges per binA block

typedef __attribute__((ext_vector_type(8))) short short8v;  // 8 bf16 (4 VGPR)
typedef __attribute__((ext_vector_type(4))) float f32x4;    // MFMA C/D

// ---------------------------------------------------------------------------
// bf16 pack helpers (RTN)
// ---------------------------------------------------------------------------
__device__ __forceinline__ unsigned int bf16rtn(float f) {
    unsigned int u = __float_as_uint(f);
    return (u + 0x7fffu + ((u >> 16) & 1u)) >> 16;
}
__device__ __forceinline__ unsigned int packbf2(float lo, float hi) {
    return bf16rtn(lo) | (bf16rtn(hi) << 16);
}

// ---------------------------------------------------------------------------
// k_prepW: split W (f32 [k][col]) into Wh + Wl bf16 stored [col][k] (B^T rows
// = MFMA B-frag layout). Also zeroes gcur.
// ---------------------------------------------------------------------------
__global__ void k_prepW(const float* __restrict__ W1, const float* __restrict__ W2,
                        unsigned short* __restrict__ Wsplit, int* __restrict__ gcur) {
    int t = blockIdx.x * 256 + threadIdx.x;   // 0..32767
    if (t < NBB) gcur[t] = 0;
    if (t >= 32768) return;
    int layer = t >> 14, idx = t & 16383;
    int i = idx >> 7, j = idx & 127;          // i = k (in), j = col (out)
    const float* Wsrc = layer ? W2 : W1;
    float w = Wsrc[i * 128 + j];
    unsigned int h = bf16rtn(w);
    float hf = __uint_as_float(h << 16);
    unsigned int l = bf16rtn(w - hf);
    unsigned short* base = Wsplit + layer * 32768;
    base[j * 128 + i] = (unsigned short)h;
    base[16384 + j * 128 + i] = (unsigned short)l;
}

// ---------------------------------------------------------------------------
// k_binA: radix partition with PACKED 4B records: pk = src | (dst&127)<<20.
// LDS scatter + global write are half of the int2 version; ushort bucket-id
// side array recovers b in the coalesced writeout.
// ---------------------------------------------------------------------------
__global__ __launch_bounds__(256) void k_binA(const int* __restrict__ ei,
                                              int* __restrict__ gcur,
                                              unsigned int* __restrict__ tmp) {
    __shared__ int hist[NBB];
    __shared__ int lbase[NBB];
    __shared__ int gbaseL[NBB];
    __shared__ int wsum[4];
    __shared__ unsigned int  bufp[CHUNK];
    __shared__ unsigned short bufb[CHUNK];
    __shared__ int totalv;

    int tid = threadIdx.x;
    int e0 = blockIdx.x * CHUNK;

    for (int i = tid; i < NBB; i += 256) hist[i] = 0;
    __syncthreads();

    unsigned int pkarr[8];
    int barr[8], parr[8];
#pragma unroll
    for (int j = 0; j < 8; ++j) {
        int e = e0 + j * 256 + tid;
        barr[j] = -1;
        if (e < N_EDGES) {
            int s = ei[e];
            int d = ei[N_EDGES + e];
            pkarr[j] = (unsigned int)s | ((unsigned int)(d & 127) << 20);
            barr[j] = d >> 7;
            parr[j] = atomicAdd(&hist[barr[j]], 1);
        }
    }
    __syncthreads();

    {   // exclusive scan of hist (thread t owns buckets 2t,2t+1); shfl scan
        int i0 = 2 * tid, i1 = i0 + 1;
        int c0 = (i0 < NBB) ? hist[i0] : 0;
        int c1 = (i1 < NBB) ? hist[i1] : 0;
        int c = c0 + c1;
        int lane = tid & 63, w = tid >> 6;
        int s = c;
#pragma unroll
        for (int d = 1; d < 64; d <<= 1) {
            int u = __shfl_up(s, d, 64);
            if (lane >= d) s += u;
        }
        if (lane == 63) wsum[w] = s;
        __syncthreads();
        int add = 0;
        for (int i = 0; i < w; ++i) add += wsum[i];
        int incl = s + add;
        int excl = incl - c;
        if (i0 < NBB) lbase[i0] = excl;
        if (i1 < NBB) lbase[i1] = excl + c0;
        if (tid == 255) totalv = incl;
    }
    for (int i = tid; i < NBB; i += 256) {
        int cnt = hist[i];
        int run = (cnt > 0) ? atomicAdd(&gcur[i], cnt) : 0;
        gbaseL[i] = i * CAPB + run;
    }
    __syncthreads();

#pragma unroll
    for (int j = 0; j < 8; ++j) {
        if (barr[j] >= 0) {
            int pos = lbase[barr[j]] + parr[j];
            bufp[pos] = pkarr[j];
            bufb[pos] = (unsigned short)barr[j];
        }
    }
    __syncthreads();

    int total = totalv;
    for (int i = tid; i < total; i += 256) {
        int b = bufb[i];
        int gpos = gbaseL[b] + (i - lbase[b]);
        if (gpos < (b + 1) * CAPB) tmp[gpos] = bufp[i];
    }
}

// ---------------------------------------------------------------------------
// k_csr: one block per bucket; per-node contiguous USHORT src lists (padded
// to 4-ushort/8B alignment) + offn/degn/dinv. Runs once, reused twice.
// ---------------------------------------------------------------------------
__global__ __launch_bounds__(256) void k_csr(const unsigned int* __restrict__ tmp,
                                             const int* __restrict__ gcur,
                                             unsigned short* __restrict__ csr,
                                             int* __restrict__ offn,
                                             int* __restrict__ degn,
                                             float* __restrict__ dinv) {
    __shared__ unsigned int raw[CAPB];
    __shared__ int lcnt[128];
    __shared__ int lbase[128];
    __shared__ int lcur[128];

    int b = blockIdx.x, tid = threadIdx.x;
    int cnt = gcur[b];
    if (cnt > CAPB) cnt = CAPB;

    if (tid < 128) { lcnt[tid] = 0; lcur[tid] = 0; }
    __syncthreads();

    const unsigned int* tmpb = tmp + (size_t)b * CAPB;
    for (int i = tid; i < cnt; i += 256) {
        unsigned int v = tmpb[i];
        raw[i] = v;
        atomicAdd(&lcnt[v >> 20], 1);
    }
    __syncthreads();

    if (tid < 64) {   // scan of 4-padded counts (keeps each list 8B-aligned)
        int c0 = lcnt[2 * tid], c1 = lcnt[2 * tid + 1];
        int p0 = (c0 + 3) & ~3, p1 = (c1 + 3) & ~3;
        int c = p0 + p1;
        int s = c;
#pragma unroll
        for (int d = 1; d < 64; d <<= 1) {
            int u = __shfl_up(s, d, 64);
            if (tid >= d) s += u;
        }
        int excl = s - c;
        lbase[2 * tid] = excl;
        lbase[2 * tid + 1] = excl + p0;
    }
    __syncthreads();

    int node = b * 128 + tid;
    if (tid < 128 && node < N_NODES) {
        offn[node] = b * CAPC + lbase[tid];
        degn[node] = lcnt[tid];
        dinv[node] = rsqrtf((float)lcnt[tid] + 1.0f);
    }

    for (int i = tid; i < cnt; i += 256) {
        unsigned int v = raw[i];
        int l = v >> 20;
        int p = atomicAdd(&lcur[l], 1);
        csr[b * CAPC + lbase[l] + p] = (unsigned short)(v & 0xFFFFFu);
    }
}

// ---------------------------------------------------------------------------
// MFMA GEMM (2-term W-split): Hout[r][c] = bf16( dinv[r] * (A[r] @ (Wh+Wl)) )
// Row-major h (round-10 layout). AF32=true: A f32. AF32=false: A bf16 rows.
// ---------------------------------------------------------------------------
template <bool AF32>
__global__ __launch_bounds__(512, 4) void k_gemm(const void* __restrict__ Ain,
                                                 const unsigned short* __restrict__ Whg,
                                                 const unsigned short* __restrict__ Wlg,
                                                 const float* __restrict__ dinv,
                                                 unsigned short* __restrict__ Hout) {
    __shared__ uint4 Al[64 * 16];   // [64 rows][128 k] bf16, XOR-swizzled
    __shared__ float ddv[64];

    int tid = threadIdx.x;
    int row0 = blockIdx.x * 64;
    int wv = tid >> 6, lane = tid & 63;
    int col = wv * 16 + (lane & 15);
    int kq = lane >> 4;

    const uint4* Bh4 = (const uint4*)Whg;
    const uint4* Bl4 = (const uint4*)Wlg;
    short8v bh[4], bl[4];
#pragma unroll
    for (int ks = 0; ks < 4; ++ks) {
        uint4 uh = Bh4[col * 16 + ks * 4 + kq];
        uint4 ul = Bl4[col * 16 + ks * 4 + kq];
        bh[ks] = *reinterpret_cast<short8v*>(&uh);
        bl[ks] = *reinterpret_cast<short8v*>(&ul);
    }

#pragma unroll
    for (int pass = 0; pass < 2; ++pass) {
        int row = (tid >> 4) + pass * 32;
        int o = tid & 15;
        int gr = row0 + row;
        uint4 u = make_uint4(0u, 0u, 0u, 0u);
        if (AF32) {
            float4 v0 = make_float4(0.f, 0.f, 0.f, 0.f), v1 = v0;
            if (gr < N_NODES) {
                const float4* A4 = (const float4*)Ain;
                v0 = A4[gr * 32 + o * 2];
                v1 = A4[gr * 32 + o * 2 + 1];
            }
            u.x = packbf2(v0.x, v0.y);
            u.y = packbf2(v0.z, v0.w);
            u.z = packbf2(v1.x, v1.y);
            u.w = packbf2(v1.z, v1.w);
        } else {
            if (gr < N_NODES) u = ((const uint4*)Ain)[gr * 16 + o];
        }
        int byte = (row * 256 + o * 16) ^ ((row & 7) << 4);
        Al[byte >> 4] = u;
    }
    if (tid < 64) {
        int gr = row0 + tid;
        ddv[tid] = (gr < N_NODES) ? dinv[gr] : 0.f;
    }
    __syncthreads();

    f32x4 acc[4];
#pragma unroll
    for (int st = 0; st < 4; ++st) acc[st] = (f32x4){0.f, 0.f, 0.f, 0.f};

#pragma unroll
    for (int st = 0; st < 4; ++st) {
        int rowl = st * 16 + (lane & 15);
        int rbase = rowl * 256;
        int swz = (rowl & 7) << 4;
#pragma unroll
        for (int ks = 0; ks < 4; ++ks) {
            int byte = (rbase + ks * 64 + kq * 16) ^ swz;
            uint4 ua = Al[byte >> 4];
            short8v a = *reinterpret_cast<short8v*>(&ua);
            acc[st] = __builtin_amdgcn_mfma_f32_16x16x32_bf16(a, bh[ks], acc[st], 0, 0, 0);
            acc[st] = __builtin_amdgcn_mfma_f32_16x16x32_bf16(a, bl[ks], acc[st], 0, 0, 0);
        }
    }

#pragma unroll
    for (int st = 0; st < 4; ++st) {
#pragma unroll
        for (int r = 0; r < 4; ++r) {
            int rowl = st * 16 + kq * 4 + r;
            int gr = row0 + rowl;
            if (gr < N_NODES) {
                float dv = ddv[rowl];
                Hout[gr * 128 + col] = (unsigned short)bf16rtn(dv * acc[st][r]);
            }
        }
    }
}

// ---------------------------------------------------------------------------
// Wave-per-node aggregation on the global ushort CSR (round-10 structure).
// 12500 blocks x 256 thr, no LDS. eg=lane>>4 (edge group), cq=lane&15
// (channel quad). 16 edges (rows) in flight per wave via ushort4 index
// loads. h pre-scaled by dinv[src] -> pure row-sum; self-term + dv + bias
// at the end. FINAL=false: relu'd bf16 rows. FINAL=true: fused final linear.
// ---------------------------------------------------------------------------
__device__ __forceinline__ void add8(float* acc, uint4 u) {
    acc[0] += __uint_as_float(u.x << 16);
    acc[1] += __uint_as_float(u.x & 0xffff0000u);
    acc[2] += __uint_as_float(u.y << 16);
    acc[3] += __uint_as_float(u.y & 0xffff0000u);
    acc[4] += __uint_as_float(u.z << 16);
    acc[5] += __uint_as_float(u.z & 0xffff0000u);
    acc[6] += __uint_as_float(u.w << 16);
    acc[7] += __uint_as_float(u.w & 0xffff0000u);
}

template <bool FINAL>
__global__ __launch_bounds__(256) void k_agg(const uint4* __restrict__ h4,
                                             const unsigned short* __restrict__ csr,
                                             const int* __restrict__ offn,
                                             const int* __restrict__ degn,
                                             const float* __restrict__ bias,
                                             const float* __restrict__ Wlin,
                                             const float* __restrict__ blin,
                                             void* __restrict__ aggout) {
    int n = (blockIdx.x * 256 + threadIdx.x) >> 6;   // grid sized exactly
    int lane = threadIdx.x & 63, eg = lane >> 4, cq = lane & 15;

    int o0 = offn[n];
    int deg = degn[n];
    int end = o0 + deg;

    uint4 us = h4[n * 16 + cq];   // self-term row: issue early

    float acc[8];
#pragma unroll
    for (int j = 0; j < 8; ++j) acc[j] = 0.f;

    int e = o0;
    for (; e + 16 <= end; e += 16) {
        ushort4 s4 = *(const ushort4*)(csr + e + 4 * eg);   // 8B-aligned
        uint4 u0 = h4[(int)s4.x * 16 + cq];
        uint4 u1 = h4[(int)s4.y * 16 + cq];
        uint4 u2 = h4[(int)s4.z * 16 + cq];
        uint4 u3 = h4[(int)s4.w * 16 + cq];
        add8(acc, u0); add8(acc, u1); add8(acc, u2); add8(acc, u3);
    }
    if (e + 8 <= end) {
        ushort2 s2 = *(const ushort2*)(csr + e + 2 * eg);   // 4B-aligned
        uint4 u0 = h4[(int)s2.x * 16 + cq];
        uint4 u1 = h4[(int)s2.y * 16 + cq];
        add8(acc, u0); add8(acc, u1);
        e += 8;
    }
    {   // tail < 8
        int r = end - e;
        int b0 = e + 2 * eg;
        if (2 * eg < r)     add8(acc, h4[(int)csr[b0] * 16 + cq]);
        if (2 * eg + 1 < r) add8(acc, h4[(int)csr[b0 + 1] * 16 + cq]);
    }
#pragma unroll
    for (int j = 0; j < 8; ++j) {
        acc[j] += __shfl_xor(acc[j], 16, 64);
        acc[j] += __shfl_xor(acc[j], 32, 64);
    }

    float dv = rsqrtf((float)deg + 1.0f);
    float4 bv0 = ((const float4*)bias)[cq * 2];
    float4 bv1 = ((const float4*)bias)[cq * 2 + 1];
    float hv[8];
    hv[0] = __uint_as_float(us.x << 16); hv[1] = __uint_as_float(us.x & 0xffff0000u);
    hv[2] = __uint_as_float(us.y << 16); hv[3] = __uint_as_float(us.y & 0xffff0000u);
    hv[4] = __uint_as_float(us.z << 16); hv[5] = __uint_as_float(us.z & 0xffff0000u);
    hv[6] = __uint_as_float(us.w << 16); hv[7] = __uint_as_float(us.w & 0xffff0000u);
    float o[8];
    o[0] = dv * (acc[0] + hv[0]) + bv0.x;
    o[1] = dv * (acc[1] + hv[1]) + bv0.y;
    o[2] = dv * (acc[2] + hv[2]) + bv0.z;
    o[3] = dv * (acc[3] + hv[3]) + bv0.w;
    o[4] = dv * (acc[4] + hv[4]) + bv1.x;
    o[5] = dv * (acc[5] + hv[5]) + bv1.y;
    o[6] = dv * (acc[6] + hv[6]) + bv1.z;
    o[7] = dv * (acc[7] + hv[7]) + bv1.w;

    if (!FINAL) {
        if (eg == 0) {   // relu + bf16 pack (bit-identical to relu-in-gemm)
            uint4 u;
            u.x = packbf2(fmaxf(o[0], 0.f), fmaxf(o[1], 0.f));
            u.y = packbf2(fmaxf(o[2], 0.f), fmaxf(o[3], 0.f));
            u.z = packbf2(fmaxf(o[4], 0.f), fmaxf(o[5], 0.f));
            u.w = packbf2(fmaxf(o[6], 0.f), fmaxf(o[7], 0.f));
            ((uint4*)aggout)[n * 16 + cq] = u;
        }
    } else {
        float4 wl0 = ((const float4*)Wlin)[cq * 2];
        float4 wl1 = ((const float4*)Wlin)[cq * 2 + 1];
        float v = fmaxf(o[0], 0.f) * wl0.x + fmaxf(o[1], 0.f) * wl0.y
                + fmaxf(o[2], 0.f) * wl0.z + fmaxf(o[3], 0.f) * wl0.w
                + fmaxf(o[4], 0.f) * wl1.x + fmaxf(o[5], 0.f) * wl1.y
                + fmaxf(o[6], 0.f) * wl1.z + fmaxf(o[7], 0.f) * wl1.w;
        v += __shfl_xor(v, 1, 64);
        v += __shfl_xor(v, 2, 64);
        v += __shfl_xor(v, 4, 64);
        v += __shfl_xor(v, 8, 64);
        if (lane == 0) ((float*)aggout)[n] = v + blin[0];
    }
}

// ---------------------------------------------------------------------------
extern "C" void kernel_launch(void* const* d_in, const int* in_sizes, int n_in,
                              void* d_out, int out_size, void* d_ws, size_t ws_size,
                              hipStream_t stream) {
    const float* x    = (const float*)d_in[0];
    const int*   ei   = (const int*)d_in[2];
    const float* W1   = (const float*)d_in[4];
    const float* b1   = (const float*)d_in[5];
    const float* W2   = (const float*)d_in[6];
    const float* b2   = (const float*)d_in[7];
    const float* Wlin = (const float*)d_in[8];
    const float* blin = (const float*)d_in[9];
    float* out = (float*)d_out;

    char* ws = (char*)d_ws;
    size_t off = 0;
    auto carve = [&](size_t bytes) -> void* {
        void* p = ws + off;
        off = (off + bytes + 255) & ~(size_t)255;
        return p;
    };
    int*   gcur = (int*)  carve(NBB * sizeof(int));
    float* dinv = (float*)carve(N_NODES * sizeof(float));
    int*   offn = (int*)  carve(N_NODES * sizeof(int));
    int*   degn = (int*)  carve(N_NODES * sizeof(int));
    unsigned int*   tmp = (unsigned int*)  carve((size_t)NBB * CAPB * sizeof(unsigned int)); // 4.8 MB
    unsigned short* csr = (unsigned short*)carve((size_t)NBB * CAPC * sizeof(unsigned short)); // 2.8 MB
    unsigned short* hbf  = (unsigned short*)carve((size_t)N_NODES * C * sizeof(unsigned short));
    unsigned short* hbf2 = (unsigned short*)carve((size_t)N_NODES * C * sizeof(unsigned short));
    unsigned short* wsplit = (unsigned short*)carve(4 * 16384 * sizeof(unsigned short));

    const int NB_A = (N_EDGES + CHUNK - 1) / CHUNK;   // 391
    const int NB_G = (N_NODES + 63) / 64;             // 782
    const int NB_W = (N_NODES * 64) / 256;            // 12500 (exact)

    const unsigned short* W1h = wsplit;
    const unsigned short* W1l = wsplit + 16384;
    const unsigned short* W2h = wsplit + 32768;
    const unsigned short* W2l = wsplit + 49152;

    // prep (zeroes gcur) -> partition -> CSR (+dinv)
    k_prepW<<<128, 256, 0, stream>>>(W1, W2, wsplit, gcur);
    k_binA<<<NB_A, 256, 0, stream>>>(ei, gcur, tmp);
    k_csr<<<NBB, 256, 0, stream>>>(tmp, gcur, csr, offn, degn, dinv);

    // Layer 1: h1 = bf16(dinv * (x @ W1)); agg1 -> relu'd bf16 rows
    k_gemm<true><<<NB_G, 512, 0, stream>>>(x, W1h, W1l, dinv, hbf);
    k_agg<false><<<NB_W, 256, 0, stream>>>((const uint4*)hbf, csr, offn, degn,
                                           b1, Wlin, blin, hbf2);
    // Layer 2: h2 = bf16(dinv * (relu(agg1) @ W2)); agg2 + fused final linear
    k_gemm<false><<<NB_G, 512, 0, stream>>>(hbf2, W2h, W2l, dinv, hbf);
    k_agg<true><<<NB_W, 256, 0, stream>>>((const uint4*)hbf, csr, offn, degn,
                                          b2, Wlin, blin, out);
}